// Round 8
// baseline (482.991 us; speedup 1.0000x reference)
//
#include <hip/hip_runtime.h>
#include <math.h>

typedef __bf16 bf16;
typedef __bf16 bf16x8 __attribute__((ext_vector_type(8)));
typedef __bf16 bf16x4 __attribute__((ext_vector_type(4)));
typedef float  f32x4  __attribute__((ext_vector_type(4)));

#define HW        16384      // 128*128
#define OUT_ELEMS 4194304    // 4*64*128*128

// padded xm: [b][m][yp=142][xp=142][c=64], pixel (y,x) at (y+7, x+7)
#define XM_ROW    (142 * 64)
#define XM_PLANE  (142 * XM_ROW)          // 1,290,496 el
// padded cat: [b][yp=130][xp=130][ch=256], pixel (y,x) at (y+1, x+1)
#define CAT_ROW   (130 * 256)
#define CAT_PLANE (130 * CAT_ROW)         // 4,326,400 el

// LDS pixel stride (elements): 64 payload + 8 pad -> 144 B
#define LPX 72

// barrier without the __syncthreads vmcnt(0) drain: lgkm drain gives cross-wave
// LDS visibility; VMEM loads stay in flight with counted vmcnt at use sites.
__device__ __forceinline__ void phase_barrier() {
  asm volatile("s_waitcnt lgkmcnt(0)" ::: "memory");
  __builtin_amdgcn_s_barrier();
  __builtin_amdgcn_sched_barrier(0);
}

// ------ weight transforms (fp32 -> bf16, tap-major) + cat_p halo zero --------
// blocks 0..2303: weight transform; blocks 2304..2561: zero cat halo.
// Safe at t=0: mask partials alias xm_p (not cat_p).
__global__ void k_wt(const float* __restrict__ kern, const float* __restrict__ w2,
                     bf16* __restrict__ kern_t, bf16* __restrict__ w2_t,
                     bf16* __restrict__ cat_p) {
  int blk = blockIdx.x;
  if (blk >= 2304) {                      // ---- halo zeroing ----
    int id = (blk - 2304) * 256 + threadIdx.x;
    if (id >= 4 * 16512) return;
    int plane = id / 16512, j = id % 16512;
    bf16* base = cat_p + (size_t)plane * CAT_PLANE;
    bf16x8 zv = {};
    if (j < 8320) {                       // rows 0 and 129, full 130 px
      int row = (j / 4160) * 129;
      int off = (j % 4160) * 8;
      *(bf16x8*)(base + (size_t)row * CAT_ROW + off) = zv;
    } else {                              // rows 1..128, cols 0 and 129
      int k = j - 8320;
      int row = 1 + (k >> 6);
      int idx = k & 63;
      int col = (idx >> 5) * 129;
      int ch8 = (idx & 31) * 8;
      *(bf16x8*)(base + (size_t)row * CAT_ROW + col * 256 + ch8) = zv;
    }
    return;
  }
  int i = blk * 256 + threadIdx.x;
  const int N1 = 4 * 3 * 9 * 64 * 64;   // 442368
  if (i < N1) {
    int c = i & 63, o = (i >> 6) & 63, tap = (i >> 12) % 9, bm = i / 36864;
    kern_t[i] = (bf16)kern[(((bm * 64 + o) * 64 + c) * 9) + tap];
  } else {
    int j = i - N1;
    if (j < 64 * 256 * 9) {
      int ch = j & 255, oc = (j >> 8) & 63, tap = j >> 14;
      w2_t[j] = (bf16)w2[(oc * 256 + ch) * 9 + tap];
    }
  }
}

// -------- mask conv stage 1: partial logits over 8-channel groups ------------
__global__ void k_mask1(const float* __restrict__ x, const float* __restrict__ mw,
                        float* __restrict__ part) {
  int y = blockIdx.x, b = blockIdx.y, cg = blockIdx.z;
  int tx = threadIdx.x;      // 0..127
  float a0 = 0.f, a1 = 0.f, a2 = 0.f;
#pragma unroll
  for (int ci = 0; ci < 8; ++ci) {
    int c = cg * 8 + ci;
    const float* xp = x + ((size_t)(b * 64 + c)) * HW;
    const float* w0 = mw + (0 * 64 + c) * 9;
    const float* w1 = mw + (1 * 64 + c) * 9;
    const float* w2 = mw + (2 * 64 + c) * 9;
#pragma unroll
    for (int ky = 0; ky < 3; ++ky) {
      int yy = y + ky - 1;
      if ((unsigned)yy >= 128u) continue;
#pragma unroll
      for (int kx = 0; kx < 3; ++kx) {
        int xx = tx + kx - 1;
        if ((unsigned)xx >= 128u) continue;
        float xv = xp[yy * 128 + xx];
        a0 += xv * w0[ky * 3 + kx];
        a1 += xv * w1[ky * 3 + kx];
        a2 += xv * w2[ky * 3 + kx];
      }
    }
  }
  size_t base = (size_t)((b * 8 + cg) * 3) * HW + y * 128 + tx;
  part[base]          = a0;
  part[base + HW]     = a1;
  part[base + 2 * HW] = a2;
}

// -------- mask conv stage 2: reduce groups + bias + softmax ------------------
__global__ void k_mask2(const float* __restrict__ part, const float* __restrict__ mb,
                        float* __restrict__ masks) {
  int y = blockIdx.x, b = blockIdx.y;
  int tx = threadIdx.x;
  float a0 = mb[0], a1 = mb[1], a2 = mb[2];
  int off = y * 128 + tx;
#pragma unroll
  for (int cg = 0; cg < 8; ++cg) {
    size_t base = (size_t)((b * 8 + cg) * 3) * HW + off;
    a0 += part[base];
    a1 += part[base + HW];
    a2 += part[base + 2 * HW];
  }
  float mx = fmaxf(a0, fmaxf(a1, a2));
  float e0 = __expf(a0 - mx), e1 = __expf(a1 - mx), e2 = __expf(a2 - mx);
  float inv = 1.0f / (e0 + e1 + e2);
  size_t base = ((size_t)b * 3) * HW + off;
  masks[base]          = e0 * inv;
  masks[base + HW]     = e1 * inv;
  masks[base + 2 * HW] = e2 * inv;
}

// -------- xm = x * mask, NCHW fp32 -> padded NHWC(c=64) bf16, incl. halo -----
__global__ void k_xmt(const float* __restrict__ x, const float* __restrict__ masks,
                      bf16* __restrict__ xm_p) {
  int yp = blockIdx.x;  // 0..141 padded row
  int m = blockIdx.y, b = blockIdx.z;
  int t = threadIdx.x;  // 256
  bf16* prow = xm_p + (size_t)(b * 3 + m) * XM_PLANE + (size_t)yp * XM_ROW;
  bf16x8 z = {};
  if (yp < 7 || yp >= 135) {          // full halo row: 142*64/8 = 1136 chunks
#pragma unroll
    for (int i = 0; i < 5; ++i) {
      int u = i * 256 + t;
      if (u < 1136) ((bf16x8*)prow)[u] = z;
    }
    return;
  }
  // side halo: 7 px * 64c = 448 el = 56 chunks each side
  if (t < 56) ((bf16x8*)prow)[t] = z;
  else if (t < 112) ((bf16x8*)(prow + 135 * 64))[t - 56] = z;

  int y = yp - 7;
  __shared__ float tile[64 * 130];
#pragma unroll
  for (int i = 0; i < 32; ++i) {
    int u = i * 256 + t;           // 0..8191
    int c = u >> 7, xx = u & 127;
    tile[c * 130 + xx] = x[((size_t)(b * 64 + c)) * HW + y * 128 + xx];
  }
  __syncthreads();
  const float* mrow = masks + ((size_t)(b * 3 + m)) * HW + y * 128;
  bf16* orow = prow + 7 * 64;
#pragma unroll
  for (int i = 0; i < 32; ++i) {
    int u = i * 256 + t;
    int c = u & 63, xx = u >> 6;
    orow[xx * 64 + c] = (bf16)(tile[c * 130 + xx] * mrow[xx]);
  }
}

// ------- branch convs: DIRECT-B implicit GEMM (no LDS, no barriers) ----------
// The old LDS staging was a pure copy (stride 64->72): every MFMA B-fragment
// (16B at (px, ch-slot)) exists verbatim in padded xm_p. Per-block B working
// set ~160KB, shared with neighbor blocks -> L1/L2-resident (m169 lesson:
// drop staging when data cache-fits). Deletes barriers, ds ops, sreg, and all
// 7.08M bank-conflict cycles. 2048 blocks x 256 thr; waves: mh = oc-half,
// wc = px-half; acc[2][4]=32 AGPR, areg 48 VGPR -> ~4 waves/SIMD, free-running.
__global__ __launch_bounds__(256, 4) void k_branch(const bf16* __restrict__ xm_p,
                                                   const bf16* __restrict__ kern_t,
                                                   bf16* __restrict__ cat_p) {
  int bid = blockIdx.x;
  int xcd = bid & 7;
  int i   = bid >> 3;          // 0..255
  int b   = xcd >> 1;
  int di  = ((xcd & 1) << 1) | (i & 1);
  int y   = i >> 1;            // 0..127
  int d   = 1 + 2 * di;        // 1,3,5,7
  int t    = threadIdx.x;
  int lane = t & 63;
  int wave = t >> 6;           // 0..3
  int mh   = wave >> 1;        // oc half (0/1)
  int wc   = wave & 1;         // px half (0/1)
  int lanelo = lane & 15;
  int quad = lane >> 4;

  const bf16* plane0 = xm_p + (size_t)(b * 3) * XM_PLANE;
  const bf16* wb0    = kern_t + (size_t)(b * 27) * 4096
                     + (mh * 2048 + lanelo * 64 + quad * 8);
  // per-lane B base offset within a padded row: pixel (7 + wc*64 + lanelo),
  // channel slot quad*8 (16B aligned)
  const int laneoff = (7 + wc * 64 + lanelo) * 64 + quad * 8;

  f32x4 acc[2][4] = {};

#pragma unroll
  for (int p = 0; p < 9; ++p) {
    int m = p / 3, ky = p % 3;
    // A-frags: this wave's 32-oc half, 12 x 16B (L1/L2-resident kern_t)
    bf16x8 areg[3][2][2];
    const bf16* wtap = wb0 + (size_t)(m * 9 + ky * 3) * 4096;
#pragma unroll
    for (int kx = 0; kx < 3; ++kx)
#pragma unroll
      for (int kci = 0; kci < 2; ++kci)
#pragma unroll
        for (int mt = 0; mt < 2; ++mt)
          areg[kx][kci][mt] = *(const bf16x8*)(wtap + kx * 4096 + mt * 1024 + kci * 32);

    // B: direct 16B global loads from the padded row (halo makes all in-bounds)
    const bf16* rowp = plane0 + (size_t)m * XM_PLANE
                     + (size_t)(y + 7 + d * (ky - 1)) * XM_ROW + laneoff;
#pragma unroll
    for (int kx = 0; kx < 3; ++kx) {
      const bf16* bp = rowp + (d * (kx - 1)) * 64;
#pragma unroll
      for (int kci = 0; kci < 2; ++kci) {
        bf16x8 bv[4];
#pragma unroll
        for (int nt = 0; nt < 4; ++nt)
          bv[nt] = *(const bf16x8*)(bp + nt * (16 * 64) + kci * 32);
        __builtin_amdgcn_s_setprio(1);
#pragma unroll
        for (int mt = 0; mt < 2; ++mt)
#pragma unroll
          for (int nt = 0; nt < 4; ++nt)
            acc[mt][nt] = __builtin_amdgcn_mfma_f32_16x16x32_bf16(areg[kx][kci][mt], bv[nt], acc[mt][nt], 0, 0, 0);
        __builtin_amdgcn_s_setprio(0);
      }
    }
  }

  // epilogue: cat_p[b][y+1][px+1][di*64 + oc]
  bf16* cp = cat_p + (size_t)b * CAT_PLANE + (size_t)(y + 1) * CAT_ROW + di * 64;
#pragma unroll
  for (int mt = 0; mt < 2; ++mt) {
#pragma unroll
    for (int nt = 0; nt < 4; ++nt) {
      int px = wc * 64 + nt * 16 + lanelo;
      bf16x4 v;
#pragma unroll
      for (int r = 0; r < 4; ++r) v[r] = (bf16)acc[mt][nt][r];
      *(bf16x4*)(cp + (size_t)(px + 1) * 256 + (mh * 32 + mt * 16 + quad * 4)) = v;
    }
  }
}

// ------- final conv + bias + BN + ReLU (R1 form: lived in both best totals) --
// block = 256 thr (4 waves), tile = 64 o x 128 px x 2 rows.
// 12 phases (ky, cq): stage 2 cat rows' 64-ch slice into LDS.
__global__ __launch_bounds__(256, 1) void k_final(const bf16* __restrict__ cat_p,
                                                  const bf16* __restrict__ w2_t,
                                                  const float* __restrict__ cb,
                                                  const float* __restrict__ gamma,
                                                  const float* __restrict__ beta,
                                                  const float* __restrict__ mean,
                                                  const float* __restrict__ var,
                                                  float* __restrict__ out) {
  __shared__ bf16 sb[2 * 130 * LPX];   // 37,440 B
  int bid = blockIdx.x;                 // 0..255
  int xcd = bid & 7;
  int b   = xcd >> 1;
  int y   = (((bid >> 3) << 1) | (xcd & 1)) * 2;   // 0,2,..,126
  int t    = threadIdx.x;
  int lane = t & 63;
  int wave = t >> 6;
  int wr   = wave >> 1;
  int wc   = wave & 1;
  int lanelo = lane & 15;
  int quad = lane >> 4;

  const bf16* cbase = cat_p + (size_t)b * CAT_PLANE;
  const bf16* wbase = w2_t + (lanelo * 256 + quad * 8);

  // prologue: staging loads for phase 0 (ky=0, cq=0): rows y, y+1, ch 0..63
  bf16x8 sreg[2][5];
#pragma unroll
  for (int rr = 0; rr < 2; ++rr) {
    const bf16* s0 = cbase + (size_t)(y + rr) * CAT_ROW;
#pragma unroll
    for (int r = 0; r < 5; ++r) {
      int u = r * 256 + t;
      if (u < 1040) sreg[rr][r] = *(const bf16x8*)(s0 + (u >> 3) * 256 + (u & 7) * 8);
    }
  }

  f32x4 acc[4][4] = {};

#pragma unroll
  for (int p = 0; p < 12; ++p) {
    int ky = p >> 2, cq = p & 3;
    // A frags: 3 kx x 2 kc x 4 mt
    bf16x8 areg[3][2][4];
#pragma unroll
    for (int kx = 0; kx < 3; ++kx)
#pragma unroll
      for (int kci = 0; kci < 2; ++kci)
#pragma unroll
        for (int mt = 0; mt < 4; ++mt)
          areg[kx][kci][mt] = *(const bf16x8*)(wbase + (size_t)((ky * 3 + kx) * 64 + mt * 16) * 256
                                               + cq * 64 + kci * 32);

    phase_barrier();
#pragma unroll
    for (int rr = 0; rr < 2; ++rr)
#pragma unroll
      for (int r = 0; r < 5; ++r) {
        int u = r * 256 + t;
        if (u < 1040) {
          int px = u >> 3, c8 = u & 7;
          *(bf16x8*)(sb + (rr * 130 + px) * LPX + c8 * 8) = sreg[rr][r];
        }
      }
    if (p < 11) {
      int pn = p + 1;
      int kyn = pn >> 2, cqn = pn & 3;
#pragma unroll
      for (int rr = 0; rr < 2; ++rr) {
        const bf16* sn = cbase + (size_t)(y + kyn + rr) * CAT_ROW + cqn * 64;
#pragma unroll
        for (int r = 0; r < 5; ++r) {
          int u = r * 256 + t;
          if (u < 1040) sreg[rr][r] = *(const bf16x8*)(sn + (u >> 3) * 256 + (u & 7) * 8);
        }
      }
    }
    phase_barrier();
#pragma unroll
    for (int kx = 0; kx < 3; ++kx) {
      int p0 = wc * 64 + lanelo + kx;
      int base = (wr * 130 + p0) * LPX + quad * 8;
#pragma unroll
      for (int kci = 0; kci < 2; ++kci) {
        bf16x8 bv[4];
#pragma unroll
        for (int nt = 0; nt < 4; ++nt)
          bv[nt] = *(const bf16x8*)(sb + base + nt * (16 * LPX) + kci * 32);
        __builtin_amdgcn_s_setprio(1);
#pragma unroll
        for (int mt = 0; mt < 4; ++mt)
#pragma unroll
          for (int nt = 0; nt < 4; ++nt)
            acc[mt][nt] = __builtin_amdgcn_mfma_f32_16x16x32_bf16(areg[kx][kci][mt], bv[nt], acc[mt][nt], 0, 0, 0);
        __builtin_amdgcn_s_setprio(0);
      }
    }
  }

#pragma unroll
  for (int mt = 0; mt < 4; ++mt) {
#pragma unroll
    for (int nt = 0; nt < 4; ++nt) {
      int px = wc * 64 + nt * 16 + lanelo;
#pragma unroll
      for (int r = 0; r < 4; ++r) {
        int oc = mt * 16 + quad * 4 + r;
        float inv = gamma[oc] * rsqrtf(var[oc] + 1e-5f);
        float v = (acc[mt][nt][r] + cb[oc]) * inv + beta[oc] - mean[oc] * inv;
        out[((size_t)(b * 64 + oc)) * HW + (y + wr) * 128 + px] = fmaxf(v, 0.0f);
      }
    }
  }
}

extern "C" void kernel_launch(void* const* d_in, const int* in_sizes, int n_in,
                              void* d_out, int out_size, void* d_ws, size_t ws_size,
                              hipStream_t stream) {
  const float* x     = (const float*)d_in[0];
  const float* kern  = (const float*)d_in[1];
  const float* mw    = (const float*)d_in[2];
  const float* mb    = (const float*)d_in[3];
  const float* w2    = (const float*)d_in[4];
  const float* cb    = (const float*)d_in[5];
  const float* gamma = (const float*)d_in[6];
  const float* beta  = (const float*)d_in[7];
  const float* mean  = (const float*)d_in[8];
  const float* var   = (const float*)d_in[9];

  float* out   = (float*)d_out;
  float* masks = out + OUT_ELEMS;

  char* ws = (char*)d_ws;
  bf16* xm_p   = (bf16*)(ws);              // 30,971,904 B
  bf16* cat_p  = (bf16*)(ws + 30971904);   // 34,611,200 B (ends 65,583,104)
  bf16* kern_t = (bf16*)(ws + 65583104);   // 884,736 B
  bf16* w2_t   = (bf16*)(ws + 66467840);   // 294,912 B -> total 66,762,752 B
  // mask partials alias xm_p region (consumed by k_mask2 before k_xmt writes)
  float* part  = (float*)(ws);             // 6,291,456 B < xm_p size

  k_wt<<<2562, 256, 0, stream>>>(kern, w2, kern_t, w2_t, cat_p);
  k_mask1<<<dim3(128, 4, 8), 128, 0, stream>>>(x, mw, part);
  k_mask2<<<dim3(128, 4), 128, 0, stream>>>(part, mb, masks);
  k_xmt<<<dim3(142, 3, 4), 256, 0, stream>>>(x, masks, xm_p);
  k_branch<<<2048, 256, 0, stream>>>(xm_p, kern_t, cat_p);
  k_final<<<256, 256, 0, stream>>>(cat_p, w2_t, cb, gamma, beta, mean, var, out);
}

// Round 9
// 310.693 us; speedup vs baseline: 1.5546x; 1.5546x over previous
//
#include <hip/hip_runtime.h>
#include <math.h>

typedef __bf16 bf16;
typedef __bf16 bf16x8 __attribute__((ext_vector_type(8)));
typedef __bf16 bf16x4 __attribute__((ext_vector_type(4)));
typedef float  f32x4  __attribute__((ext_vector_type(4)));

#define HW        16384      // 128*128
#define OUT_ELEMS 4194304    // 4*64*128*128

// padded xm: [b][m][yp=142][xp=142][c=64], pixel (y,x) at (y+7, x+7)
#define XM_ROW    (142 * 64)
#define XM_PLANE  (142 * XM_ROW)          // 1,290,496 el
// padded cat: [b][yp=130][xp=130][ch=256], pixel (y,x) at (y+1, x+1)
#define CAT_ROW   (130 * 256)
#define CAT_PLANE (130 * CAT_ROW)         // 4,326,400 el

// LDS pixel stride (elements): 64 payload + 8 pad -> 144 B
#define LPX 72

// barrier without the __syncthreads vmcnt(0) drain: lgkm drain gives cross-wave
// LDS visibility; VMEM loads stay in flight with counted vmcnt at use sites.
__device__ __forceinline__ void phase_barrier() {
  asm volatile("s_waitcnt lgkmcnt(0)" ::: "memory");
  __builtin_amdgcn_s_barrier();
  __builtin_amdgcn_sched_barrier(0);
}

// ------ weight transforms (fp32 -> bf16, tap-major) + cat_p halo zero --------
// blocks 0..2303: weight transform; blocks 2304..2561: zero cat halo.
// Safe at t=0: mask partials alias xm_p (not cat_p).
__global__ void k_wt(const float* __restrict__ kern, const float* __restrict__ w2,
                     bf16* __restrict__ kern_t, bf16* __restrict__ w2_t,
                     bf16* __restrict__ cat_p) {
  int blk = blockIdx.x;
  if (blk >= 2304) {                      // ---- halo zeroing ----
    int id = (blk - 2304) * 256 + threadIdx.x;
    if (id >= 4 * 16512) return;
    int plane = id / 16512, j = id % 16512;
    bf16* base = cat_p + (size_t)plane * CAT_PLANE;
    bf16x8 zv = {};
    if (j < 8320) {                       // rows 0 and 129, full 130 px
      int row = (j / 4160) * 129;
      int off = (j % 4160) * 8;
      *(bf16x8*)(base + (size_t)row * CAT_ROW + off) = zv;
    } else {                              // rows 1..128, cols 0 and 129
      int k = j - 8320;
      int row = 1 + (k >> 6);
      int idx = k & 63;
      int col = (idx >> 5) * 129;
      int ch8 = (idx & 31) * 8;
      *(bf16x8*)(base + (size_t)row * CAT_ROW + col * 256 + ch8) = zv;
    }
    return;
  }
  int i = blk * 256 + threadIdx.x;
  const int N1 = 4 * 3 * 9 * 64 * 64;   // 442368
  if (i < N1) {
    int c = i & 63, o = (i >> 6) & 63, tap = (i >> 12) % 9, bm = i / 36864;
    kern_t[i] = (bf16)kern[(((bm * 64 + o) * 64 + c) * 9) + tap];
  } else {
    int j = i - N1;
    if (j < 64 * 256 * 9) {
      int ch = j & 255, oc = (j >> 8) & 63, tap = j >> 14;
      w2_t[j] = (bf16)w2[(oc * 256 + ch) * 9 + tap];
    }
  }
}

// -------- mask conv stage 1: partial logits over 8-channel groups ------------
__global__ void k_mask1(const float* __restrict__ x, const float* __restrict__ mw,
                        float* __restrict__ part) {
  int y = blockIdx.x, b = blockIdx.y, cg = blockIdx.z;
  int tx = threadIdx.x;      // 0..127
  float a0 = 0.f, a1 = 0.f, a2 = 0.f;
#pragma unroll
  for (int ci = 0; ci < 8; ++ci) {
    int c = cg * 8 + ci;
    const float* xp = x + ((size_t)(b * 64 + c)) * HW;
    const float* w0 = mw + (0 * 64 + c) * 9;
    const float* w1 = mw + (1 * 64 + c) * 9;
    const float* w2 = mw + (2 * 64 + c) * 9;
#pragma unroll
    for (int ky = 0; ky < 3; ++ky) {
      int yy = y + ky - 1;
      if ((unsigned)yy >= 128u) continue;
#pragma unroll
      for (int kx = 0; kx < 3; ++kx) {
        int xx = tx + kx - 1;
        if ((unsigned)xx >= 128u) continue;
        float xv = xp[yy * 128 + xx];
        a0 += xv * w0[ky * 3 + kx];
        a1 += xv * w1[ky * 3 + kx];
        a2 += xv * w2[ky * 3 + kx];
      }
    }
  }
  size_t base = (size_t)((b * 8 + cg) * 3) * HW + y * 128 + tx;
  part[base]          = a0;
  part[base + HW]     = a1;
  part[base + 2 * HW] = a2;
}

// -------- mask conv stage 2: reduce groups + bias + softmax ------------------
__global__ void k_mask2(const float* __restrict__ part, const float* __restrict__ mb,
                        float* __restrict__ masks) {
  int y = blockIdx.x, b = blockIdx.y;
  int tx = threadIdx.x;
  float a0 = mb[0], a1 = mb[1], a2 = mb[2];
  int off = y * 128 + tx;
#pragma unroll
  for (int cg = 0; cg < 8; ++cg) {
    size_t base = (size_t)((b * 8 + cg) * 3) * HW + off;
    a0 += part[base];
    a1 += part[base + HW];
    a2 += part[base + 2 * HW];
  }
  float mx = fmaxf(a0, fmaxf(a1, a2));
  float e0 = __expf(a0 - mx), e1 = __expf(a1 - mx), e2 = __expf(a2 - mx);
  float inv = 1.0f / (e0 + e1 + e2);
  size_t base = ((size_t)b * 3) * HW + off;
  masks[base]          = e0 * inv;
  masks[base + HW]     = e1 * inv;
  masks[base + 2 * HW] = e2 * inv;
}

// -------- xm = x * mask, NCHW fp32 -> padded NHWC(c=64) bf16, incl. halo -----
__global__ void k_xmt(const float* __restrict__ x, const float* __restrict__ masks,
                      bf16* __restrict__ xm_p) {
  int yp = blockIdx.x;  // 0..141 padded row
  int m = blockIdx.y, b = blockIdx.z;
  int t = threadIdx.x;  // 256
  bf16* prow = xm_p + (size_t)(b * 3 + m) * XM_PLANE + (size_t)yp * XM_ROW;
  bf16x8 z = {};
  if (yp < 7 || yp >= 135) {          // full halo row: 142*64/8 = 1136 chunks
#pragma unroll
    for (int i = 0; i < 5; ++i) {
      int u = i * 256 + t;
      if (u < 1136) ((bf16x8*)prow)[u] = z;
    }
    return;
  }
  // side halo: 7 px * 64c = 448 el = 56 chunks each side
  if (t < 56) ((bf16x8*)prow)[t] = z;
  else if (t < 112) ((bf16x8*)(prow + 135 * 64))[t - 56] = z;

  int y = yp - 7;
  __shared__ float tile[64 * 130];
#pragma unroll
  for (int i = 0; i < 32; ++i) {
    int u = i * 256 + t;           // 0..8191
    int c = u >> 7, xx = u & 127;
    tile[c * 130 + xx] = x[((size_t)(b * 64 + c)) * HW + y * 128 + xx];
  }
  __syncthreads();
  const float* mrow = masks + ((size_t)(b * 3 + m)) * HW + y * 128;
  bf16* orow = prow + 7 * 64;
#pragma unroll
  for (int i = 0; i < 32; ++i) {
    int u = i * 256 + t;
    int c = u & 63, xx = u >> 6;
    orow[xx * 64 + c] = (bf16)(tile[c * 130 + xx] * mrow[xx]);
  }
}

// ------- branch convs: LDS-staged implicit GEMM (REVERTED to 124.8us form) ---
// Direct-B (R8) failed: per-lane 16B gathers at 128B stride through L1 are
// 5-10x worse than coalesced-stage + bank-parallel ds_read. Keep LDS staging.
// 2048 blocks x 256 thr, tile = 64 oc x 128 px x 1 row. Waves M/N-split:
// mh = oc-half (32 oc), wc = px-half (64 px) -> 3 waves/SIMD (12 waves/CU).
// 9 phases (m,ky), one barrier each, staging pipelined 2 phases ahead.
__global__ __launch_bounds__(256, 3) void k_branch(const bf16* __restrict__ xm_p,
                                                   const bf16* __restrict__ kern_t,
                                                   bf16* __restrict__ cat_p) {
  __shared__ bf16 sb[2][142 * LPX];   // 2 x 20,448 B = 40,896 B
  int bid = blockIdx.x;
  int xcd = bid & 7;
  int i   = bid >> 3;          // 0..255
  int b   = xcd >> 1;
  int di  = ((xcd & 1) << 1) | (i & 1);
  int y   = i >> 1;            // 0..127
  int d   = 1 + 2 * di;        // 1,3,5,7
  int t    = threadIdx.x;
  int lane = t & 63;
  int wave = t >> 6;           // 0..3
  int mh   = wave >> 1;        // oc half (0/1)
  int wc   = wave & 1;         // px half (0/1)
  int lanelo = lane & 15;
  int quad = lane >> 4;

  const bf16* plane0 = xm_p + (size_t)(b * 3) * XM_PLANE;
  const bf16* wb0    = kern_t + (size_t)(b * 27) * 4096
                     + (mh * 2048 + lanelo * 64 + quad * 8);

  bf16x8 sreg[5];
  // prologue: phase 0 (m=0,ky=0) row -> buf0; issue phase 1 (m=0,ky=1)
  {
    const bf16* s0 = plane0 + (size_t)(y + 7 - d) * XM_ROW;
#pragma unroll
    for (int r = 0; r < 5; ++r) {
      int u = r * 256 + t;
      if (u < 1136) sreg[r] = *(const bf16x8*)(s0 + u * 8);
    }
#pragma unroll
    for (int r = 0; r < 5; ++r) {
      int u = r * 256 + t;
      if (u < 1136) {
        int pxL = u >> 3, c8 = u & 7;
        *(bf16x8*)(&sb[0][pxL * LPX + c8 * 8]) = sreg[r];
      }
    }
    const bf16* s1 = plane0 + (size_t)(y + 7) * XM_ROW;
#pragma unroll
    for (int r = 0; r < 5; ++r) {
      int u = r * 256 + t;
      if (u < 1136) sreg[r] = *(const bf16x8*)(s1 + u * 8);
    }
  }
  phase_barrier();

  f32x4 acc[2][4] = {};

#pragma unroll
  for (int p = 0; p < 9; ++p) {
    int m = p / 3, ky = p % 3;
    // A-frag loads: this wave's 32-oc half, 12 x 16B
    bf16x8 areg[3][2][2];
    const bf16* wtap = wb0 + (size_t)(m * 9 + ky * 3) * 4096;
#pragma unroll
    for (int kx = 0; kx < 3; ++kx)
#pragma unroll
      for (int kci = 0; kci < 2; ++kci)
#pragma unroll
        for (int mt = 0; mt < 2; ++mt)
          areg[kx][kci][mt] = *(const bf16x8*)(wtap + kx * 4096 + mt * 1024 + kci * 32);

    // write phase p+1 data (loaded at p-1) to the other buffer
    if (p < 8) {
#pragma unroll
      for (int r = 0; r < 5; ++r) {
        int u = r * 256 + t;
        if (u < 1136) {
          int pxL = u >> 3, c8 = u & 7;
          *(bf16x8*)(&sb[(p + 1) & 1][pxL * LPX + c8 * 8]) = sreg[r];
        }
      }
    }
    // issue staging loads for phase p+2
    if (p < 7) {
      int pn = p + 2;
      int mn = pn / 3, kyn = pn % 3;
      const bf16* sn = plane0 + (size_t)mn * XM_PLANE
                     + (size_t)(y + 7 + d * (kyn - 1)) * XM_ROW;
#pragma unroll
      for (int r = 0; r < 5; ++r) {
        int u = r * 256 + t;
        if (u < 1136) sreg[r] = *(const bf16x8*)(sn + u * 8);
      }
    }
    // compute from buf[p&1]: 3 kx x 2 kc x (2 mt x 4 nt) MFMA
#pragma unroll
    for (int kx = 0; kx < 3; ++kx) {
      int p0 = 7 + d * (kx - 1) + wc * 64 + lanelo;
      int base = p0 * LPX + quad * 8;
#pragma unroll
      for (int kci = 0; kci < 2; ++kci) {
        bf16x8 bv[4];
#pragma unroll
        for (int nt = 0; nt < 4; ++nt)
          bv[nt] = *(const bf16x8*)(&sb[p & 1][base + nt * (16 * LPX) + kci * 32]);
        __builtin_amdgcn_s_setprio(1);
#pragma unroll
        for (int mt = 0; mt < 2; ++mt)
#pragma unroll
          for (int nt = 0; nt < 4; ++nt)
            acc[mt][nt] = __builtin_amdgcn_mfma_f32_16x16x32_bf16(areg[kx][kci][mt], bv[nt], acc[mt][nt], 0, 0, 0);
        __builtin_amdgcn_s_setprio(0);
      }
    }
    if (p < 8) phase_barrier();
  }

  // epilogue: cat_p[b][y+1][px+1][di*64 + oc]
  bf16* cp = cat_p + (size_t)b * CAT_PLANE + (size_t)(y + 1) * CAT_ROW + di * 64;
#pragma unroll
  for (int mt = 0; mt < 2; ++mt) {
#pragma unroll
    for (int nt = 0; nt < 4; ++nt) {
      int px = wc * 64 + nt * 16 + lanelo;
      bf16x4 v;
#pragma unroll
      for (int r = 0; r < 4; ++r) v[r] = (bf16)acc[mt][nt][r];
      *(bf16x4*)(cp + (size_t)(px + 1) * 256 + (mh * 32 + mt * 16 + quad * 4)) = v;
    }
  }
}

// ------- final conv + bias + BN + ReLU, v4: 4-phase cq staging ---------------
// 256 blocks x 256 thr (4 waves, 1 block/CU). tile = 64 oc x 128 px x 2 rows.
// 4 phases (cq = 64-ch quarter): stage ALL 4 input rows' cq-slice (66,560 B)
// into dbuf LDS (149,760 B total), compute all 3 ky from it. vs R1 form:
// barriers 24 -> 4, staged bytes 400 -> 266 KB/block (1.0x ideal), staging
// loads hidden under a full compute phase (k_branch's proven pipeline).
__global__ __launch_bounds__(256, 1) void k_final(const bf16* __restrict__ cat_p,
                                                  const bf16* __restrict__ w2_t,
                                                  const float* __restrict__ cb,
                                                  const float* __restrict__ gamma,
                                                  const float* __restrict__ beta,
                                                  const float* __restrict__ mean,
                                                  const float* __restrict__ var,
                                                  float* __restrict__ out) {
  __shared__ bf16 sb[2][4 * 130 * LPX];   // 2 x 74,880 B = 149,760 B
  int bid = blockIdx.x;                 // 0..255
  int xcd = bid & 7;
  int b   = xcd >> 1;
  int y   = (((bid >> 3) << 1) | (xcd & 1)) * 2;   // 0,2,..,126
  int t    = threadIdx.x;
  int lane = t & 63;
  int wave = t >> 6;
  int wr   = wave >> 1;
  int wc   = wave & 1;
  int lanelo = lane & 15;
  int quad = lane >> 4;

  const bf16* cbase = cat_p + (size_t)b * CAT_PLANE;
  const bf16* wbase = w2_t + (lanelo * 256 + quad * 8);

  bf16x8 sreg[4][5];   // 4 rows x 5 chunks (u < 1040 guard) = 80 VGPR
  // prologue: load cq=0 (rows y..y+3, ch 0..63) -> buf0; issue cq=1 loads
#pragma unroll
  for (int rr = 0; rr < 4; ++rr) {
    const bf16* s0 = cbase + (size_t)(y + rr) * CAT_ROW;
#pragma unroll
    for (int r = 0; r < 5; ++r) {
      int u = r * 256 + t;
      if (u < 1040) sreg[rr][r] = *(const bf16x8*)(s0 + (u >> 3) * 256 + (u & 7) * 8);
    }
  }
#pragma unroll
  for (int rr = 0; rr < 4; ++rr)
#pragma unroll
    for (int r = 0; r < 5; ++r) {
      int u = r * 256 + t;
      if (u < 1040) {
        int px = u >> 3, c8 = u & 7;
        *(bf16x8*)(&sb[0][(rr * 130 + px) * LPX + c8 * 8]) = sreg[rr][r];
      }
    }
#pragma unroll
  for (int rr = 0; rr < 4; ++rr) {
    const bf16* s1 = cbase + (size_t)(y + rr) * CAT_ROW + 64;
#pragma unroll
    for (int r = 0; r < 5; ++r) {
      int u = r * 256 + t;
      if (u < 1040) sreg[rr][r] = *(const bf16x8*)(s1 + (u >> 3) * 256 + (u & 7) * 8);
    }
  }
  phase_barrier();

  f32x4 acc[4][4] = {};

#pragma unroll
  for (int p = 0; p < 4; ++p) {
    int cq = p;
    // write cq p+1 data (loaded at p-1) to the other buffer
    if (p < 3) {
#pragma unroll
      for (int rr = 0; rr < 4; ++rr)
#pragma unroll
        for (int r = 0; r < 5; ++r) {
          int u = r * 256 + t;
          if (u < 1040) {
            int px = u >> 3, c8 = u & 7;
            *(bf16x8*)(&sb[(p + 1) & 1][(rr * 130 + px) * LPX + c8 * 8]) = sreg[rr][r];
          }
        }
    }
    // issue staging loads for cq p+2
    if (p < 2) {
      int cqn = p + 2;
#pragma unroll
      for (int rr = 0; rr < 4; ++rr) {
        const bf16* sn = cbase + (size_t)(y + rr) * CAT_ROW + cqn * 64;
#pragma unroll
        for (int r = 0; r < 5; ++r) {
          int u = r * 256 + t;
          if (u < 1040) sreg[rr][r] = *(const bf16x8*)(sn + (u >> 3) * 256 + (u & 7) * 8);
        }
      }
    }
    // compute all 3 ky from buf[p&1]
#pragma unroll
    for (int ky = 0; ky < 3; ++ky) {
      // A frags for (ky, cq): 3 kx x 2 kc x 4 mt
      bf16x8 areg[3][2][4];
#pragma unroll
      for (int kx = 0; kx < 3; ++kx)
#pragma unroll
        for (int kci = 0; kci < 2; ++kci)
#pragma unroll
          for (int mt = 0; mt < 4; ++mt)
            areg[kx][kci][mt] = *(const bf16x8*)(wbase + (size_t)((ky * 3 + kx) * 64 + mt * 16) * 256
                                                 + cq * 64 + kci * 32);
#pragma unroll
      for (int kx = 0; kx < 3; ++kx) {
        int p0 = wc * 64 + lanelo + kx;
        int base = ((ky + wr) * 130 + p0) * LPX + quad * 8;
#pragma unroll
        for (int kci = 0; kci < 2; ++kci) {
          bf16x8 bv[4];
#pragma unroll
          for (int nt = 0; nt < 4; ++nt)
            bv[nt] = *(const bf16x8*)(&sb[p & 1][base + nt * (16 * LPX) + kci * 32]);
          __builtin_amdgcn_s_setprio(1);
#pragma unroll
          for (int mt = 0; mt < 4; ++mt)
#pragma unroll
            for (int nt = 0; nt < 4; ++nt)
              acc[mt][nt] = __builtin_amdgcn_mfma_f32_16x16x32_bf16(areg[kx][kci][mt], bv[nt], acc[mt][nt], 0, 0, 0);
          __builtin_amdgcn_s_setprio(0);
        }
      }
    }
    if (p < 3) phase_barrier();
  }

#pragma unroll
  for (int mt = 0; mt < 4; ++mt) {
#pragma unroll
    for (int nt = 0; nt < 4; ++nt) {
      int px = wc * 64 + nt * 16 + lanelo;
#pragma unroll
      for (int r = 0; r < 4; ++r) {
        int oc = mt * 16 + quad * 4 + r;
        float inv = gamma[oc] * rsqrtf(var[oc] + 1e-5f);
        float v = (acc[mt][nt][r] + cb[oc]) * inv + beta[oc] - mean[oc] * inv;
        out[((size_t)(b * 64 + oc)) * HW + (y + wr) * 128 + px] = fmaxf(v, 0.0f);
      }
    }
  }
}

extern "C" void kernel_launch(void* const* d_in, const int* in_sizes, int n_in,
                              void* d_out, int out_size, void* d_ws, size_t ws_size,
                              hipStream_t stream) {
  const float* x     = (const float*)d_in[0];
  const float* kern  = (const float*)d_in[1];
  const float* mw    = (const float*)d_in[2];
  const float* mb    = (const float*)d_in[3];
  const float* w2    = (const float*)d_in[4];
  const float* cb    = (const float*)d_in[5];
  const float* gamma = (const float*)d_in[6];
  const float* beta  = (const float*)d_in[7];
  const float* mean  = (const float*)d_in[8];
  const float* var   = (const float*)d_in[9];

  float* out   = (float*)d_out;
  float* masks = out + OUT_ELEMS;

  char* ws = (char*)d_ws;
  bf16* xm_p   = (bf16*)(ws);              // 30,971,904 B
  bf16* cat_p  = (bf16*)(ws + 30971904);   // 34,611,200 B (ends 65,583,104)
  bf16* kern_t = (bf16*)(ws + 65583104);   // 884,736 B
  bf16* w2_t   = (bf16*)(ws + 66467840);   // 294,912 B -> total 66,762,752 B
  // mask partials alias xm_p region (consumed by k_mask2 before k_xmt writes)
  float* part  = (float*)(ws);             // 6,291,456 B < xm_p size

  k_wt<<<2562, 256, 0, stream>>>(kern, w2, kern_t, w2_t, cat_p);
  k_mask1<<<dim3(128, 4, 8), 128, 0, stream>>>(x, mw, part);
  k_mask2<<<dim3(128, 4), 128, 0, stream>>>(part, mb, masks);
  k_xmt<<<dim3(142, 3, 4), 256, 0, stream>>>(x, masks, xm_p);
  k_branch<<<2048, 256, 0, stream>>>(xm_p, kern_t, cat_p);
  k_final<<<256, 256, 0, stream>>>(cat_p, w2_t, cb, gamma, beta, mean, var, out);
}

// Round 10
// 273.932 us; speedup vs baseline: 1.7632x; 1.1342x over previous
//
#include <hip/hip_runtime.h>
#include <math.h>

typedef __bf16 bf16;
typedef __bf16 bf16x8 __attribute__((ext_vector_type(8)));
typedef __bf16 bf16x4 __attribute__((ext_vector_type(4)));
typedef float  f32x4  __attribute__((ext_vector_type(4)));

#define HW        16384      // 128*128
#define OUT_ELEMS 4194304    // 4*64*128*128

// padded xm: [b][m][yp=142][xp=142][c=64], pixel (y,x) at (y+7, x+7)
#define XM_ROW    (142 * 64)
#define XM_PLANE  (142 * XM_ROW)          // 1,290,496 el
// padded cat: [b][yp=130][xp=130][ch=256], pixel (y,x) at (y+1, x+1)
#define CAT_ROW   (130 * 256)
#define CAT_PLANE (130 * CAT_ROW)         // 4,326,400 el

// LDS pixel stride (elements): 64 payload + 8 pad -> 144 B
#define LPX 72

// barrier without the __syncthreads vmcnt(0) drain (k_final only now)
__device__ __forceinline__ void phase_barrier() {
  asm volatile("s_waitcnt lgkmcnt(0)" ::: "memory");
  __builtin_amdgcn_s_barrier();
  __builtin_amdgcn_sched_barrier(0);
}

// ------ weight transforms (fp32 -> bf16) + cat_p halo zero -------------------
// kern_t NEW layout (lane-major, coalesced A-frag loads):
//   kern_t[(bm*9+tap)*4096 + (mt*2+kci)*512 + lane*8 + j]
//   where o = mt*16 + (lane&15), c = kci*32 + (lane>>4)*8 + j
// Each MFMA A-fragment load becomes one contiguous 1KB wave-load.
__global__ void k_wt(const float* __restrict__ kern, const float* __restrict__ w2,
                     bf16* __restrict__ kern_t, bf16* __restrict__ w2_t,
                     bf16* __restrict__ cat_p) {
  int blk = blockIdx.x;
  if (blk >= 2304) {                      // ---- halo zeroing ----
    int id = (blk - 2304) * 256 + threadIdx.x;
    if (id >= 4 * 16512) return;
    int plane = id / 16512, j = id % 16512;
    bf16* base = cat_p + (size_t)plane * CAT_PLANE;
    bf16x8 zv = {};
    if (j < 8320) {                       // rows 0 and 129, full 130 px
      int row = (j / 4160) * 129;
      int off = (j % 4160) * 8;
      *(bf16x8*)(base + (size_t)row * CAT_ROW + off) = zv;
    } else {                              // rows 1..128, cols 0 and 129
      int k = j - 8320;
      int row = 1 + (k >> 6);
      int idx = k & 63;
      int col = (idx >> 5) * 129;
      int ch8 = (idx & 31) * 8;
      *(bf16x8*)(base + (size_t)row * CAT_ROW + col * 256 + ch8) = zv;
    }
    return;
  }
  int i = blk * 256 + threadIdx.x;
  const int N1 = 4 * 3 * 9 * 64 * 64;   // 442368
  if (i < N1) {
    int j    = i & 7;
    int lane = (i >> 3) & 63;
    int km   = (i >> 9) & 7;            // kci = km&1, mt = km>>1
    int tap  = (i >> 12) % 9;
    int bm   = i / 36864;
    int o = (km >> 1) * 16 + (lane & 15);
    int c = (km & 1) * 32 + (lane >> 4) * 8 + j;
    kern_t[i] = (bf16)kern[(((bm * 64 + o) * 64 + c) * 9) + tap];
  } else {
    int j = i - N1;
    if (j < 64 * 256 * 9) {
      int ch = j & 255, oc = (j >> 8) & 63, tap = j >> 14;
      w2_t[j] = (bf16)w2[(oc * 256 + ch) * 9 + tap];
    }
  }
}

// -------- mask conv stage 1: partial logits over 8-channel groups ------------
__global__ void k_mask1(const float* __restrict__ x, const float* __restrict__ mw,
                        float* __restrict__ part) {
  int y = blockIdx.x, b = blockIdx.y, cg = blockIdx.z;
  int tx = threadIdx.x;      // 0..127
  float a0 = 0.f, a1 = 0.f, a2 = 0.f;
#pragma unroll
  for (int ci = 0; ci < 8; ++ci) {
    int c = cg * 8 + ci;
    const float* xp = x + ((size_t)(b * 64 + c)) * HW;
    const float* w0 = mw + (0 * 64 + c) * 9;
    const float* w1 = mw + (1 * 64 + c) * 9;
    const float* w2 = mw + (2 * 64 + c) * 9;
#pragma unroll
    for (int ky = 0; ky < 3; ++ky) {
      int yy = y + ky - 1;
      if ((unsigned)yy >= 128u) continue;
#pragma unroll
      for (int kx = 0; kx < 3; ++kx) {
        int xx = tx + kx - 1;
        if ((unsigned)xx >= 128u) continue;
        float xv = xp[yy * 128 + xx];
        a0 += xv * w0[ky * 3 + kx];
        a1 += xv * w1[ky * 3 + kx];
        a2 += xv * w2[ky * 3 + kx];
      }
    }
  }
  size_t base = (size_t)((b * 8 + cg) * 3) * HW + y * 128 + tx;
  part[base]          = a0;
  part[base + HW]     = a1;
  part[base + 2 * HW] = a2;
}

// -------- mask conv stage 2: reduce groups + bias + softmax ------------------
__global__ void k_mask2(const float* __restrict__ part, const float* __restrict__ mb,
                        float* __restrict__ masks) {
  int y = blockIdx.x, b = blockIdx.y;
  int tx = threadIdx.x;
  float a0 = mb[0], a1 = mb[1], a2 = mb[2];
  int off = y * 128 + tx;
#pragma unroll
  for (int cg = 0; cg < 8; ++cg) {
    size_t base = (size_t)((b * 8 + cg) * 3) * HW + off;
    a0 += part[base];
    a1 += part[base + HW];
    a2 += part[base + 2 * HW];
  }
  float mx = fmaxf(a0, fmaxf(a1, a2));
  float e0 = __expf(a0 - mx), e1 = __expf(a1 - mx), e2 = __expf(a2 - mx);
  float inv = 1.0f / (e0 + e1 + e2);
  size_t base = ((size_t)b * 3) * HW + off;
  masks[base]          = e0 * inv;
  masks[base + HW]     = e1 * inv;
  masks[base + 2 * HW] = e2 * inv;
}

// -------- xm = x * mask, NCHW fp32 -> padded NHWC(c=64) bf16, incl. halo -----
__global__ void k_xmt(const float* __restrict__ x, const float* __restrict__ masks,
                      bf16* __restrict__ xm_p) {
  int yp = blockIdx.x;  // 0..141 padded row
  int m = blockIdx.y, b = blockIdx.z;
  int t = threadIdx.x;  // 256
  bf16* prow = xm_p + (size_t)(b * 3 + m) * XM_PLANE + (size_t)yp * XM_ROW;
  bf16x8 z = {};
  if (yp < 7 || yp >= 135) {          // full halo row: 142*64/8 = 1136 chunks
#pragma unroll
    for (int i = 0; i < 5; ++i) {
      int u = i * 256 + t;
      if (u < 1136) ((bf16x8*)prow)[u] = z;
    }
    return;
  }
  // side halo: 7 px * 64c = 448 el = 56 chunks each side
  if (t < 56) ((bf16x8*)prow)[t] = z;
  else if (t < 112) ((bf16x8*)(prow + 135 * 64))[t - 56] = z;

  int y = yp - 7;
  __shared__ float tile[64 * 130];
#pragma unroll
  for (int i = 0; i < 32; ++i) {
    int u = i * 256 + t;           // 0..8191
    int c = u >> 7, xx = u & 127;
    tile[c * 130 + xx] = x[((size_t)(b * 64 + c)) * HW + y * 128 + xx];
  }
  __syncthreads();
  const float* mrow = masks + ((size_t)(b * 3 + m)) * HW + y * 128;
  bf16* orow = prow + 7 * 64;
#pragma unroll
  for (int i = 0; i < 32; ++i) {
    int u = i * 256 + t;
    int c = u & 63, xx = u >> 6;
    orow[xx * 64 + c] = (bf16)(tile[c * 130 + xx] * mrow[xx]);
  }
}

// ------- branch convs: wave-autonomous implicit GEMM, ZERO barriers ----------
// Diagnosis: all pipes <35% busy; the limiter was barrier-coupled lockstep.
// Each wave owns a PRIVATE dbuf LDS region (48px span covers its 32px +/- d
// taps) and self-stages: global->reg (2 phases ahead) -> ds_write own buf ->
// ds_read own buf -> MFMA. No cross-wave sharing => no barriers; ordering via
// compiler-counted vmcnt/lgkm. Waves: wq = px-quarter, full 64 oc (acc[4][2]).
// A-frags from lane-major kern_t: each load = 1 coalesced 1KB wave-load.
// 2048 blocks x 256 thr; LDS 55,296 B/block -> 2 blocks/CU, 8 decoupled waves.
__global__ __launch_bounds__(256, 2) void k_branch(const bf16* __restrict__ xm_p,
                                                   const bf16* __restrict__ kern_t,
                                                   bf16* __restrict__ cat_p) {
  __shared__ bf16 sb[4][2][48 * LPX];   // 4 waves x dbuf x 6,912 B = 55,296 B
  int bid = blockIdx.x;
  int xcd = bid & 7;
  int i   = bid >> 3;          // 0..255
  int b   = xcd >> 1;
  int di  = ((xcd & 1) << 1) | (i & 1);
  int y   = i >> 1;            // 0..127
  int d   = 1 + 2 * di;        // 1,3,5,7
  int t    = threadIdx.x;
  int lane = t & 63;
  int wq   = t >> 6;           // px quarter 0..3
  int lanelo = lane & 15;
  int quad = lane >> 4;

  const bf16* plane0 = xm_p + (size_t)(b * 3) * XM_PLANE;
  const bf16* wb0    = kern_t + (size_t)(b * 27) * 4096 + lane * 8;
  const int gp0 = wq * 32 + 7 - d;     // leftmost staged padded-px of this wave

  bf16* mysb0 = &sb[wq][0][0];
  bf16* mysb1 = &sb[wq][1][0];

  bf16x8 sreg[6];   // 48px x 64ch = 384 chunks of 16B = 6 per lane
  // prologue: phase 0 (m=0,ky=0) -> buf0; issue phase 1 (m=0,ky=1) loads
  {
    const bf16* s0 = plane0 + (size_t)(y + 7 - d) * XM_ROW + gp0 * 64;
#pragma unroll
    for (int r = 0; r < 6; ++r) sreg[r] = *(const bf16x8*)(s0 + (r * 64 + lane) * 8);
#pragma unroll
    for (int r = 0; r < 6; ++r) {
      int u = r * 64 + lane;
      *(bf16x8*)(mysb0 + (u >> 3) * LPX + (u & 7) * 8) = sreg[r];
    }
    const bf16* s1 = plane0 + (size_t)(y + 7) * XM_ROW + gp0 * 64;
#pragma unroll
    for (int r = 0; r < 6; ++r) sreg[r] = *(const bf16x8*)(s1 + (r * 64 + lane) * 8);
  }

  f32x4 acc[4][2] = {};

#pragma unroll
  for (int p = 0; p < 9; ++p) {
    int m = p / 3, ky = p % 3;
    // A-frags: 3 kx x 2 kci x 4 mt, each one coalesced 1KB wave-load
    bf16x8 areg[3][2][4];
    const bf16* wtap = wb0 + (size_t)(m * 9 + ky * 3) * 4096;
#pragma unroll
    for (int kx = 0; kx < 3; ++kx)
#pragma unroll
      for (int kci = 0; kci < 2; ++kci)
#pragma unroll
        for (int mt = 0; mt < 4; ++mt)
          areg[kx][kci][mt] = *(const bf16x8*)(wtap + kx * 4096 + (mt * 2 + kci) * 512);

    // write phase p+1 (loaded at p-1) into the other private buffer
    if (p < 8) {
      bf16* wbuf = ((p + 1) & 1) ? mysb1 : mysb0;
#pragma unroll
      for (int r = 0; r < 6; ++r) {
        int u = r * 64 + lane;
        *(bf16x8*)(wbuf + (u >> 3) * LPX + (u & 7) * 8) = sreg[r];
      }
    }
    // issue staging loads for phase p+2
    if (p < 7) {
      int pn = p + 2;
      int mn = pn / 3, kyn = pn % 3;
      const bf16* sn = plane0 + (size_t)mn * XM_PLANE
                     + (size_t)(y + 7 + d * (kyn - 1)) * XM_ROW + gp0 * 64;
#pragma unroll
      for (int r = 0; r < 6; ++r) sreg[r] = *(const bf16x8*)(sn + (r * 64 + lane) * 8);
    }
    // compute from private buf[p&1]; local px = lanelo + d*kx (+ nt*16)
    const bf16* rbuf = (p & 1) ? mysb1 : mysb0;
#pragma unroll
    for (int kx = 0; kx < 3; ++kx) {
      int lpx0 = lanelo + d * kx;
#pragma unroll
      for (int kci = 0; kci < 2; ++kci) {
        bf16x8 bv[2];
#pragma unroll
        for (int nt = 0; nt < 2; ++nt)
          bv[nt] = *(const bf16x8*)(rbuf + (lpx0 + nt * 16) * LPX + quad * 8 + kci * 32);
        __builtin_amdgcn_s_setprio(1);
#pragma unroll
        for (int mt = 0; mt < 4; ++mt)
#pragma unroll
          for (int nt = 0; nt < 2; ++nt)
            acc[mt][nt] = __builtin_amdgcn_mfma_f32_16x16x32_bf16(areg[kx][kci][mt], bv[nt], acc[mt][nt], 0, 0, 0);
        __builtin_amdgcn_s_setprio(0);
      }
    }
  }

  // epilogue: cat_p[b][y+1][px+1][di*64 + oc]
  bf16* cp = cat_p + (size_t)b * CAT_PLANE + (size_t)(y + 1) * CAT_ROW + di * 64;
#pragma unroll
  for (int mt = 0; mt < 4; ++mt) {
#pragma unroll
    for (int nt = 0; nt < 2; ++nt) {
      int px = wq * 32 + nt * 16 + lanelo;
      bf16x4 v;
#pragma unroll
      for (int r = 0; r < 4; ++r) v[r] = (bf16)acc[mt][nt][r];
      *(bf16x4*)(cp + (size_t)(px + 1) * 256 + (mt * 16 + quad * 4)) = v;
    }
  }
}

// ------- final conv + bias + BN + ReLU, v4: 4-phase cq staging (unchanged) ---
__global__ __launch_bounds__(256, 1) void k_final(const bf16* __restrict__ cat_p,
                                                  const bf16* __restrict__ w2_t,
                                                  const float* __restrict__ cb,
                                                  const float* __restrict__ gamma,
                                                  const float* __restrict__ beta,
                                                  const float* __restrict__ mean,
                                                  const float* __restrict__ var,
                                                  float* __restrict__ out) {
  __shared__ bf16 sb[2][4 * 130 * LPX];   // 2 x 74,880 B = 149,760 B
  int bid = blockIdx.x;                 // 0..255
  int xcd = bid & 7;
  int b   = xcd >> 1;
  int y   = (((bid >> 3) << 1) | (xcd & 1)) * 2;   // 0,2,..,126
  int t    = threadIdx.x;
  int lane = t & 63;
  int wave = t >> 6;
  int wr   = wave >> 1;
  int wc   = wave & 1;
  int lanelo = lane & 15;
  int quad = lane >> 4;

  const bf16* cbase = cat_p + (size_t)b * CAT_PLANE;
  const bf16* wbase = w2_t + (lanelo * 256 + quad * 8);

  bf16x8 sreg[4][5];
#pragma unroll
  for (int rr = 0; rr < 4; ++rr) {
    const bf16* s0 = cbase + (size_t)(y + rr) * CAT_ROW;
#pragma unroll
    for (int r = 0; r < 5; ++r) {
      int u = r * 256 + t;
      if (u < 1040) sreg[rr][r] = *(const bf16x8*)(s0 + (u >> 3) * 256 + (u & 7) * 8);
    }
  }
#pragma unroll
  for (int rr = 0; rr < 4; ++rr)
#pragma unroll
    for (int r = 0; r < 5; ++r) {
      int u = r * 256 + t;
      if (u < 1040) {
        int px = u >> 3, c8 = u & 7;
        *(bf16x8*)(&sb[0][(rr * 130 + px) * LPX + c8 * 8]) = sreg[rr][r];
      }
    }
#pragma unroll
  for (int rr = 0; rr < 4; ++rr) {
    const bf16* s1 = cbase + (size_t)(y + rr) * CAT_ROW + 64;
#pragma unroll
    for (int r = 0; r < 5; ++r) {
      int u = r * 256 + t;
      if (u < 1040) sreg[rr][r] = *(const bf16x8*)(s1 + (u >> 3) * 256 + (u & 7) * 8);
    }
  }
  phase_barrier();

  f32x4 acc[4][4] = {};

#pragma unroll
  for (int p = 0; p < 4; ++p) {
    int cq = p;
    if (p < 3) {
#pragma unroll
      for (int rr = 0; rr < 4; ++rr)
#pragma unroll
        for (int r = 0; r < 5; ++r) {
          int u = r * 256 + t;
          if (u < 1040) {
            int px = u >> 3, c8 = u & 7;
            *(bf16x8*)(&sb[(p + 1) & 1][(rr * 130 + px) * LPX + c8 * 8]) = sreg[rr][r];
          }
        }
    }
    if (p < 2) {
      int cqn = p + 2;
#pragma unroll
      for (int rr = 0; rr < 4; ++rr) {
        const bf16* sn = cbase + (size_t)(y + rr) * CAT_ROW + cqn * 64;
#pragma unroll
        for (int r = 0; r < 5; ++r) {
          int u = r * 256 + t;
          if (u < 1040) sreg[rr][r] = *(const bf16x8*)(sn + (u >> 3) * 256 + (u & 7) * 8);
        }
      }
    }
#pragma unroll
    for (int ky = 0; ky < 3; ++ky) {
      bf16x8 areg[3][2][4];
#pragma unroll
      for (int kx = 0; kx < 3; ++kx)
#pragma unroll
        for (int kci = 0; kci < 2; ++kci)
#pragma unroll
          for (int mt = 0; mt < 4; ++mt)
            areg[kx][kci][mt] = *(const bf16x8*)(wbase + (size_t)((ky * 3 + kx) * 64 + mt * 16) * 256
                                                 + cq * 64 + kci * 32);
#pragma unroll
      for (int kx = 0; kx < 3; ++kx) {
        int p0 = wc * 64 + lanelo + kx;
        int base = ((ky + wr) * 130 + p0) * LPX + quad * 8;
#pragma unroll
        for (int kci = 0; kci < 2; ++kci) {
          bf16x8 bv[4];
#pragma unroll
          for (int nt = 0; nt < 4; ++nt)
            bv[nt] = *(const bf16x8*)(&sb[p & 1][base + nt * (16 * LPX) + kci * 32]);
          __builtin_amdgcn_s_setprio(1);
#pragma unroll
          for (int mt = 0; mt < 4; ++mt)
#pragma unroll
            for (int nt = 0; nt < 4; ++nt)
              acc[mt][nt] = __builtin_amdgcn_mfma_f32_16x16x32_bf16(areg[kx][kci][mt], bv[nt], acc[mt][nt], 0, 0, 0);
          __builtin_amdgcn_s_setprio(0);
        }
      }
    }
    if (p < 3) phase_barrier();
  }

#pragma unroll
  for (int mt = 0; mt < 4; ++mt) {
#pragma unroll
    for (int nt = 0; nt < 4; ++nt) {
      int px = wc * 64 + nt * 16 + lanelo;
#pragma unroll
      for (int r = 0; r < 4; ++r) {
        int oc = mt * 16 + quad * 4 + r;
        float inv = gamma[oc] * rsqrtf(var[oc] + 1e-5f);
        float v = (acc[mt][nt][r] + cb[oc]) * inv + beta[oc] - mean[oc] * inv;
        out[((size_t)(b * 64 + oc)) * HW + (y + wr) * 128 + px] = fmaxf(v, 0.0f);
      }
    }
  }
}

extern "C" void kernel_launch(void* const* d_in, const int* in_sizes, int n_in,
                              void* d_out, int out_size, void* d_ws, size_t ws_size,
                              hipStream_t stream) {
  const float* x     = (const float*)d_in[0];
  const float* kern  = (const float*)d_in[1];
  const float* mw    = (const float*)d_in[2];
  const float* mb    = (const float*)d_in[3];
  const float* w2    = (const float*)d_in[4];
  const float* cb    = (const float*)d_in[5];
  const float* gamma = (const float*)d_in[6];
  const float* beta  = (const float*)d_in[7];
  const float* mean  = (const float*)d_in[8];
  const float* var   = (const float*)d_in[9];

  float* out   = (float*)d_out;
  float* masks = out + OUT_ELEMS;

  char* ws = (char*)d_ws;
  bf16* xm_p   = (bf16*)(ws);              // 30,971,904 B
  bf16* cat_p  = (bf16*)(ws + 30971904);   // 34,611,200 B (ends 65,583,104)
  bf16* kern_t = (bf16*)(ws + 65583104);   // 884,736 B
  bf16* w2_t   = (bf16*)(ws + 66467840);   // 294,912 B -> total 66,762,752 B
  // mask partials alias xm_p region (consumed by k_mask2 before k_xmt writes)
  float* part  = (float*)(ws);             // 6,291,456 B < xm_p size

  k_wt<<<2562, 256, 0, stream>>>(kern, w2, kern_t, w2_t, cat_p);
  k_mask1<<<dim3(128, 4, 8), 128, 0, stream>>>(x, mw, part);
  k_mask2<<<dim3(128, 4), 128, 0, stream>>>(part, mb, masks);
  k_xmt<<<dim3(142, 3, 4), 256, 0, stream>>>(x, masks, xm_p);
  k_branch<<<2048, 256, 0, stream>>>(xm_p, kern_t, cat_p);
  k_final<<<256, 256, 0, stream>>>(cat_p, w2_t, cb, gamma, beta, mean, var, out);
}

// Round 11
// 257.712 us; speedup vs baseline: 1.8741x; 1.0629x over previous
//
#include <hip/hip_runtime.h>
#include <math.h>

typedef __bf16 bf16;
typedef __bf16 bf16x8 __attribute__((ext_vector_type(8)));
typedef __bf16 bf16x4 __attribute__((ext_vector_type(4)));
typedef float  f32x4  __attribute__((ext_vector_type(4)));

#define HW        16384      // 128*128
#define OUT_ELEMS 4194304    // 4*64*128*128

// padded xm: [b][m][yp=142][xp=142][c=64], pixel (y,x) at (y+7, x+7)
#define XM_ROW    (142 * 64)
#define XM_PLANE  (142 * XM_ROW)          // 1,290,496 el
// padded cat: [b][yp=130][xp=130][ch=256], pixel (y,x) at (y+1, x+1)
#define CAT_ROW   (130 * 256)
#define CAT_PLANE (130 * CAT_ROW)         // 4,326,400 el

// LDS pixel stride (elements): 64 payload + 8 pad -> 144 B
#define LPX 72

// ------ weight transforms (fp32 -> bf16) + cat_p halo zero -------------------
// kern_t lane-major (r10 layout): kern_t[(bm*9+tap)*4096 + (mt*2+kci)*512 + lane*8 + j]
//   o = mt*16 + (lane&15), c = kci*32 + (lane>>4)*8 + j
// w2_t NEW lane-major layout (same recipe):
//   w2_t[((tap*4 + cq)*8 + mt*2+kci)*512 + lane*8 + j]
//   oc = mt*16 + (lane&15), ch = cq*64 + kci*32 + (lane>>4)*8 + j
// Every A-fragment load becomes one contiguous 1KB wave-load.
__global__ void k_wt(const float* __restrict__ kern, const float* __restrict__ w2,
                     bf16* __restrict__ kern_t, bf16* __restrict__ w2_t,
                     bf16* __restrict__ cat_p) {
  int blk = blockIdx.x;
  if (blk >= 2304) {                      // ---- halo zeroing ----
    int id = (blk - 2304) * 256 + threadIdx.x;
    if (id >= 4 * 16512) return;
    int plane = id / 16512, j = id % 16512;
    bf16* base = cat_p + (size_t)plane * CAT_PLANE;
    bf16x8 zv = {};
    if (j < 8320) {                       // rows 0 and 129, full 130 px
      int row = (j / 4160) * 129;
      int off = (j % 4160) * 8;
      *(bf16x8*)(base + (size_t)row * CAT_ROW + off) = zv;
    } else {                              // rows 1..128, cols 0 and 129
      int k = j - 8320;
      int row = 1 + (k >> 6);
      int idx = k & 63;
      int col = (idx >> 5) * 129;
      int ch8 = (idx & 31) * 8;
      *(bf16x8*)(base + (size_t)row * CAT_ROW + col * 256 + ch8) = zv;
    }
    return;
  }
  int i = blk * 256 + threadIdx.x;
  const int N1 = 4 * 3 * 9 * 64 * 64;   // 442368
  if (i < N1) {
    int j    = i & 7;
    int lane = (i >> 3) & 63;
    int km   = (i >> 9) & 7;            // kci = km&1, mt = km>>1
    int tap  = (i >> 12) % 9;
    int bm   = i / 36864;
    int o = (km >> 1) * 16 + (lane & 15);
    int c = (km & 1) * 32 + (lane >> 4) * 8 + j;
    kern_t[i] = (bf16)kern[(((bm * 64 + o) * 64 + c) * 9) + tap];
  } else {
    int j = i - N1;
    if (j < 64 * 256 * 9) {             // 147,456 el
      int j8   = j & 7;
      int lane = (j >> 3) & 63;
      int km   = (j >> 9) & 7;          // kci = km&1, mt = km>>1
      int cq   = (j >> 12) & 3;
      int tap  = j >> 14;               // 0..8
      int oc = (km >> 1) * 16 + (lane & 15);
      int ch = cq * 64 + (km & 1) * 32 + (lane >> 4) * 8 + j8;
      w2_t[j] = (bf16)w2[(oc * 256 + ch) * 9 + tap];
    }
  }
}

// -------- mask conv stage 1: partial logits over 8-channel groups ------------
__global__ void k_mask1(const float* __restrict__ x, const float* __restrict__ mw,
                        float* __restrict__ part) {
  int y = blockIdx.x, b = blockIdx.y, cg = blockIdx.z;
  int tx = threadIdx.x;      // 0..127
  float a0 = 0.f, a1 = 0.f, a2 = 0.f;
#pragma unroll
  for (int ci = 0; ci < 8; ++ci) {
    int c = cg * 8 + ci;
    const float* xp = x + ((size_t)(b * 64 + c)) * HW;
    const float* w0 = mw + (0 * 64 + c) * 9;
    const float* w1 = mw + (1 * 64 + c) * 9;
    const float* w2 = mw + (2 * 64 + c) * 9;
#pragma unroll
    for (int ky = 0; ky < 3; ++ky) {
      int yy = y + ky - 1;
      if ((unsigned)yy >= 128u) continue;
#pragma unroll
      for (int kx = 0; kx < 3; ++kx) {
        int xx = tx + kx - 1;
        if ((unsigned)xx >= 128u) continue;
        float xv = xp[yy * 128 + xx];
        a0 += xv * w0[ky * 3 + kx];
        a1 += xv * w1[ky * 3 + kx];
        a2 += xv * w2[ky * 3 + kx];
      }
    }
  }
  size_t base = (size_t)((b * 8 + cg) * 3) * HW + y * 128 + tx;
  part[base]          = a0;
  part[base + HW]     = a1;
  part[base + 2 * HW] = a2;
}

// -------- mask conv stage 2: reduce groups + bias + softmax ------------------
__global__ void k_mask2(const float* __restrict__ part, const float* __restrict__ mb,
                        float* __restrict__ masks) {
  int y = blockIdx.x, b = blockIdx.y;
  int tx = threadIdx.x;
  float a0 = mb[0], a1 = mb[1], a2 = mb[2];
  int off = y * 128 + tx;
#pragma unroll
  for (int cg = 0; cg < 8; ++cg) {
    size_t base = (size_t)((b * 8 + cg) * 3) * HW + off;
    a0 += part[base];
    a1 += part[base + HW];
    a2 += part[base + 2 * HW];
  }
  float mx = fmaxf(a0, fmaxf(a1, a2));
  float e0 = __expf(a0 - mx), e1 = __expf(a1 - mx), e2 = __expf(a2 - mx);
  float inv = 1.0f / (e0 + e1 + e2);
  size_t base = ((size_t)b * 3) * HW + off;
  masks[base]          = e0 * inv;
  masks[base + HW]     = e1 * inv;
  masks[base + 2 * HW] = e2 * inv;
}

// -------- xm = x * mask, NCHW fp32 -> padded NHWC(c=64) bf16, incl. halo -----
__global__ void k_xmt(const float* __restrict__ x, const float* __restrict__ masks,
                      bf16* __restrict__ xm_p) {
  int yp = blockIdx.x;  // 0..141 padded row
  int m = blockIdx.y, b = blockIdx.z;
  int t = threadIdx.x;  // 256
  bf16* prow = xm_p + (size_t)(b * 3 + m) * XM_PLANE + (size_t)yp * XM_ROW;
  bf16x8 z = {};
  if (yp < 7 || yp >= 135) {          // full halo row: 142*64/8 = 1136 chunks
#pragma unroll
    for (int i = 0; i < 5; ++i) {
      int u = i * 256 + t;
      if (u < 1136) ((bf16x8*)prow)[u] = z;
    }
    return;
  }
  // side halo: 7 px * 64c = 448 el = 56 chunks each side
  if (t < 56) ((bf16x8*)prow)[t] = z;
  else if (t < 112) ((bf16x8*)(prow + 135 * 64))[t - 56] = z;

  int y = yp - 7;
  __shared__ float tile[64 * 130];
#pragma unroll
  for (int i = 0; i < 32; ++i) {
    int u = i * 256 + t;           // 0..8191
    int c = u >> 7, xx = u & 127;
    tile[c * 130 + xx] = x[((size_t)(b * 64 + c)) * HW + y * 128 + xx];
  }
  __syncthreads();
  const float* mrow = masks + ((size_t)(b * 3 + m)) * HW + y * 128;
  bf16* orow = prow + 7 * 64;
#pragma unroll
  for (int i = 0; i < 32; ++i) {
    int u = i * 256 + t;
    int c = u & 63, xx = u >> 6;
    orow[xx * 64 + c] = (bf16)(tile[c * 130 + xx] * mrow[xx]);
  }
}

// ------- branch convs: wave-autonomous implicit GEMM (r10 WIN, unchanged) ----
__global__ __launch_bounds__(256, 2) void k_branch(const bf16* __restrict__ xm_p,
                                                   const bf16* __restrict__ kern_t,
                                                   bf16* __restrict__ cat_p) {
  __shared__ bf16 sb[4][2][48 * LPX];   // 4 waves x dbuf x 6,912 B = 55,296 B
  int bid = blockIdx.x;
  int xcd = bid & 7;
  int i   = bid >> 3;          // 0..255
  int b   = xcd >> 1;
  int di  = ((xcd & 1) << 1) | (i & 1);
  int y   = i >> 1;            // 0..127
  int d   = 1 + 2 * di;        // 1,3,5,7
  int t    = threadIdx.x;
  int lane = t & 63;
  int wq   = t >> 6;           // px quarter 0..3
  int lanelo = lane & 15;
  int quad = lane >> 4;

  const bf16* plane0 = xm_p + (size_t)(b * 3) * XM_PLANE;
  const bf16* wb0    = kern_t + (size_t)(b * 27) * 4096 + lane * 8;
  const int gp0 = wq * 32 + 7 - d;     // leftmost staged padded-px of this wave

  bf16* mysb0 = &sb[wq][0][0];
  bf16* mysb1 = &sb[wq][1][0];

  bf16x8 sreg[6];   // 48px x 64ch = 384 chunks of 16B = 6 per lane
  // prologue: phase 0 (m=0,ky=0) -> buf0; issue phase 1 (m=0,ky=1) loads
  {
    const bf16* s0 = plane0 + (size_t)(y + 7 - d) * XM_ROW + gp0 * 64;
#pragma unroll
    for (int r = 0; r < 6; ++r) sreg[r] = *(const bf16x8*)(s0 + (r * 64 + lane) * 8);
#pragma unroll
    for (int r = 0; r < 6; ++r) {
      int u = r * 64 + lane;
      *(bf16x8*)(mysb0 + (u >> 3) * LPX + (u & 7) * 8) = sreg[r];
    }
    const bf16* s1 = plane0 + (size_t)(y + 7) * XM_ROW + gp0 * 64;
#pragma unroll
    for (int r = 0; r < 6; ++r) sreg[r] = *(const bf16x8*)(s1 + (r * 64 + lane) * 8);
  }

  f32x4 acc[4][2] = {};

#pragma unroll
  for (int p = 0; p < 9; ++p) {
    int m = p / 3, ky = p % 3;
    // A-frags: 3 kx x 2 kci x 4 mt, each one coalesced 1KB wave-load
    bf16x8 areg[3][2][4];
    const bf16* wtap = wb0 + (size_t)(m * 9 + ky * 3) * 4096;
#pragma unroll
    for (int kx = 0; kx < 3; ++kx)
#pragma unroll
      for (int kci = 0; kci < 2; ++kci)
#pragma unroll
        for (int mt = 0; mt < 4; ++mt)
          areg[kx][kci][mt] = *(const bf16x8*)(wtap + kx * 4096 + (mt * 2 + kci) * 512);

    // write phase p+1 (loaded at p-1) into the other private buffer
    if (p < 8) {
      bf16* wbuf = ((p + 1) & 1) ? mysb1 : mysb0;
#pragma unroll
      for (int r = 0; r < 6; ++r) {
        int u = r * 64 + lane;
        *(bf16x8*)(wbuf + (u >> 3) * LPX + (u & 7) * 8) = sreg[r];
      }
    }
    // issue staging loads for phase p+2
    if (p < 7) {
      int pn = p + 2;
      int mn = pn / 3, kyn = pn % 3;
      const bf16* sn = plane0 + (size_t)mn * XM_PLANE
                     + (size_t)(y + 7 + d * (kyn - 1)) * XM_ROW + gp0 * 64;
#pragma unroll
      for (int r = 0; r < 6; ++r) sreg[r] = *(const bf16x8*)(sn + (r * 64 + lane) * 8);
    }
    // compute from private buf[p&1]; local px = lanelo + d*kx (+ nt*16)
    const bf16* rbuf = (p & 1) ? mysb1 : mysb0;
#pragma unroll
    for (int kx = 0; kx < 3; ++kx) {
      int lpx0 = lanelo + d * kx;
#pragma unroll
      for (int kci = 0; kci < 2; ++kci) {
        bf16x8 bv[2];
#pragma unroll
        for (int nt = 0; nt < 2; ++nt)
          bv[nt] = *(const bf16x8*)(rbuf + (lpx0 + nt * 16) * LPX + quad * 8 + kci * 32);
        __builtin_amdgcn_s_setprio(1);
#pragma unroll
        for (int mt = 0; mt < 4; ++mt)
#pragma unroll
          for (int nt = 0; nt < 2; ++nt)
            acc[mt][nt] = __builtin_amdgcn_mfma_f32_16x16x32_bf16(areg[kx][kci][mt], bv[nt], acc[mt][nt], 0, 0, 0);
        __builtin_amdgcn_s_setprio(0);
      }
    }
  }

  // epilogue: cat_p[b][y+1][px+1][di*64 + oc]
  bf16* cp = cat_p + (size_t)b * CAT_PLANE + (size_t)(y + 1) * CAT_ROW + di * 64;
#pragma unroll
  for (int mt = 0; mt < 4; ++mt) {
#pragma unroll
    for (int nt = 0; nt < 2; ++nt) {
      int px = wq * 32 + nt * 16 + lanelo;
      bf16x4 v;
#pragma unroll
      for (int r = 0; r < 4; ++r) v[r] = (bf16)acc[mt][nt][r];
      *(bf16x4*)(cp + (size_t)(px + 1) * 256 + (mt * 16 + quad * 4)) = v;
    }
  }
}

// ------- final conv + bias + BN + ReLU, v5: wave-autonomous (r10 template) ---
// 512 blocks x 256 thr (2 blocks/CU exactly). Each wave owns 32 px x 64 oc
// (acc[4][2]) + a PRIVATE dbuf LDS strip (40px x LPX x 2 = 11,520 B; block
// 46,080 B). 12 phases (cq x ky), each stages one cat row's 64-ch x 40-px
// slice global->reg (2 ahead) -> private ds_write -> ds_read -> MFMA.
// ZERO barriers. A-frags from lane-major w2_t: 1KB coalesced wave-loads.
__global__ __launch_bounds__(256, 2) void k_final(const bf16* __restrict__ cat_p,
                                                  const bf16* __restrict__ w2_t,
                                                  const float* __restrict__ cb,
                                                  const float* __restrict__ gamma,
                                                  const float* __restrict__ beta,
                                                  const float* __restrict__ mean,
                                                  const float* __restrict__ var,
                                                  float* __restrict__ out) {
  __shared__ bf16 sb[4][2][40 * LPX];   // 4 waves x dbuf x 5,760 B = 46,080 B
  int bid = blockIdx.x;                 // 0..511
  int xcd = bid & 7;
  int b   = xcd >> 1;
  int y   = ((bid >> 3) << 1) | (xcd & 1);   // 0..127
  int t    = threadIdx.x;
  int lane = t & 63;
  int wq   = t >> 6;           // px quarter 0..3
  int lanelo = lane & 15;
  int quad = lane >> 4;

  // wave's staged span starts at padded px wq*32 (reads use local px 0..33)
  const bf16* cb2 = cat_p + (size_t)b * CAT_PLANE + (size_t)(wq * 32) * 256;
  const bf16* wb0 = w2_t + lane * 8;

  bf16* mysb0 = &sb[wq][0][0];
  bf16* mysb1 = &sb[wq][1][0];

  bf16x8 sreg[5];   // 40px x 64ch = 320 chunks of 16B = 5 per lane
  // prologue: phase 0 (cq=0,ky=0) -> buf0; issue phase 1 (cq=0,ky=1) loads
  {
    const bf16* s0 = cb2 + (size_t)y * CAT_ROW;
#pragma unroll
    for (int r = 0; r < 5; ++r) {
      int u = r * 64 + lane;
      sreg[r] = *(const bf16x8*)(s0 + (u >> 3) * 256 + (u & 7) * 8);
    }
#pragma unroll
    for (int r = 0; r < 5; ++r) {
      int u = r * 64 + lane;
      *(bf16x8*)(mysb0 + (u >> 3) * LPX + (u & 7) * 8) = sreg[r];
    }
    const bf16* s1 = cb2 + (size_t)(y + 1) * CAT_ROW;
#pragma unroll
    for (int r = 0; r < 5; ++r) {
      int u = r * 64 + lane;
      sreg[r] = *(const bf16x8*)(s1 + (u >> 3) * 256 + (u & 7) * 8);
    }
  }

  f32x4 acc[4][2] = {};

#pragma unroll
  for (int p = 0; p < 12; ++p) {
    int cq = p / 3, ky = p % 3;
    // A-frags: 3 kx x 2 kci x 4 mt, each one coalesced 1KB wave-load
    bf16x8 areg[3][2][4];
#pragma unroll
    for (int kx = 0; kx < 3; ++kx) {
      const bf16* wt = wb0 + (size_t)(((ky * 3 + kx) * 4 + cq) * 8) * 512;
#pragma unroll
      for (int kci = 0; kci < 2; ++kci)
#pragma unroll
        for (int mt = 0; mt < 4; ++mt)
          areg[kx][kci][mt] = *(const bf16x8*)(wt + (mt * 2 + kci) * 512);
    }

    // write phase p+1 (loaded at p-1) into the other private buffer
    if (p < 11) {
      bf16* wbuf = ((p + 1) & 1) ? mysb1 : mysb0;
#pragma unroll
      for (int r = 0; r < 5; ++r) {
        int u = r * 64 + lane;
        *(bf16x8*)(wbuf + (u >> 3) * LPX + (u & 7) * 8) = sreg[r];
      }
    }
    // issue staging loads for phase p+2
    if (p < 10) {
      int pn = p + 2;
      int cqn = pn / 3, kyn = pn % 3;
      const bf16* sn = cb2 + (size_t)(y + kyn) * CAT_ROW + cqn * 64;
#pragma unroll
      for (int r = 0; r < 5; ++r) {
        int u = r * 64 + lane;
        sreg[r] = *(const bf16x8*)(sn + (u >> 3) * 256 + (u & 7) * 8);
      }
    }
    // compute from private buf[p&1]; local px = lanelo + kx (+ nt*16)
    const bf16* rbuf = (p & 1) ? mysb1 : mysb0;
#pragma unroll
    for (int kx = 0; kx < 3; ++kx) {
      int lpx0 = lanelo + kx;
#pragma unroll
      for (int kci = 0; kci < 2; ++kci) {
        bf16x8 bv[2];
#pragma unroll
        for (int nt = 0; nt < 2; ++nt)
          bv[nt] = *(const bf16x8*)(rbuf + (lpx0 + nt * 16) * LPX + quad * 8 + kci * 32);
        __builtin_amdgcn_s_setprio(1);
#pragma unroll
        for (int mt = 0; mt < 4; ++mt)
#pragma unroll
          for (int nt = 0; nt < 2; ++nt)
            acc[mt][nt] = __builtin_amdgcn_mfma_f32_16x16x32_bf16(areg[kx][kci][mt], bv[nt], acc[mt][nt], 0, 0, 0);
        __builtin_amdgcn_s_setprio(0);
      }
    }
  }

  // epilogue: bias + BN + ReLU -> out[b][oc][y][px]
#pragma unroll
  for (int mt = 0; mt < 4; ++mt) {
#pragma unroll
    for (int nt = 0; nt < 2; ++nt) {
      int px = wq * 32 + nt * 16 + lanelo;
#pragma unroll
      for (int r = 0; r < 4; ++r) {
        int oc = mt * 16 + quad * 4 + r;
        float inv = gamma[oc] * rsqrtf(var[oc] + 1e-5f);
        float v = (acc[mt][nt][r] + cb[oc]) * inv + beta[oc] - mean[oc] * inv;
        out[((size_t)(b * 64 + oc)) * HW + y * 128 + px] = fmaxf(v, 0.0f);
      }
    }
  }
}

extern "C" void kernel_launch(void* const* d_in, const int* in_sizes, int n_in,
                              void* d_out, int out_size, void* d_ws, size_t ws_size,
                              hipStream_t stream) {
  const float* x     = (const float*)d_in[0];
  const float* kern  = (const float*)d_in[1];
  const float* mw    = (const float*)d_in[2];
  const float* mb    = (const float*)d_in[3];
  const float* w2    = (const float*)d_in[4];
  const float* cb    = (const float*)d_in[5];
  const float* gamma = (const float*)d_in[6];
  const float* beta  = (const float*)d_in[7];
  const float* mean  = (const float*)d_in[8];
  const float* var   = (const float*)d_in[9];

  float* out   = (float*)d_out;
  float* masks = out + OUT_ELEMS;

  char* ws = (char*)d_ws;
  bf16* xm_p   = (bf16*)(ws);              // 30,971,904 B
  bf16* cat_p  = (bf16*)(ws + 30971904);   // 34,611,200 B (ends 65,583,104)
  bf16* kern_t = (bf16*)(ws + 65583104);   // 884,736 B
  bf16* w2_t   = (bf16*)(ws + 66467840);   // 294,912 B -> total 66,762,752 B
  // mask partials alias xm_p region (consumed by k_mask2 before k_xmt writes)
  float* part  = (float*)(ws);             // 6,291,456 B < xm_p size

  k_wt<<<2562, 256, 0, stream>>>(kern, w2, kern_t, w2_t, cat_p);
  k_mask1<<<dim3(128, 4, 8), 128, 0, stream>>>(x, mw, part);
  k_mask2<<<dim3(128, 4), 128, 0, stream>>>(part, mb, masks);
  k_xmt<<<dim3(142, 3, 4), 256, 0, stream>>>(x, masks, xm_p);
  k_branch<<<2048, 256, 0, stream>>>(xm_p, kern_t, cat_p);
  k_final<<<512, 256, 0, stream>>>(cat_p, w2_t, cb, gamma, beta, mean, var, out);
}